// Round 6
// baseline (314.975 us; speedup 1.0000x reference)
//
#include <hip/hip_runtime.h>
#include <hip/hip_bf16.h>

#define B_ 64
#define S_ 512
#define H_ 1024
#define M_ 26
#define E_ 676

typedef short bf16x8 __attribute__((ext_vector_type(8)));
typedef float f32x4 __attribute__((ext_vector_type(4)));

__device__ __forceinline__ void gload16(const void* g, void* l) {
    __builtin_amdgcn_global_load_lds((const __attribute__((address_space(1))) unsigned int*)g,
                                     (__attribute__((address_space(3))) unsigned int*)l,
                                     16, 0, 0);
}

// fast tanh: 1 - 2/(exp(2x)+1)
__device__ __forceinline__ float tanh_fast(float x) {
    float e = __expf(2.0f * x);
    return 1.0f - 2.0f * __builtin_amdgcn_rcpf(e + 1.0f);
}

// ================= STAGE 1: seg | prep | count+econ | cls GEMM =================
// block partition (long-pole first): [0,1024) seg, [1024,4096) prep,
// 4096 count, 4097 econ, [4098,4354) cls
__global__ __launch_bounds__(256) void k_stage1(
    const float* __restrict__ seq, const int* __restrict__ off,
    const float* __restrict__ Wnaf, const float* __restrict__ Wcd,
    const float* __restrict__ Wnd, const float* __restrict__ Wed,
    const float* __restrict__ bed, const float* __restrict__ Weo,
    const float* __restrict__ beo,
    __hip_bfloat16* __restrict__ Wt, int* __restrict__ count,
    float* __restrict__ econ, float* __restrict__ naf, float* __restrict__ cdh,
    float* __restrict__ node_sum) {
    __shared__ float smem[2048];
    int bid = blockIdx.x;
    int tid = threadIdx.x;

    if (bid < 1024) {
        // ---- segment sums, 8-deep load pipeline ----
        int chunk = bid & 15, b = bid >> 4;
        int* offs = (int*)smem;                 // [25]
        int* cs = (int*)smem + 28;
        if (tid < M_ - 1) offs[tid] = off[b * (M_ - 1) + tid];
        __syncthreads();
        if (tid == 0) {
            int c = 0;
            while (c < M_ - 1 && offs[c] > 0) c++;
            cs[0] = c; cs[1] = (c > 0) ? offs[c - 1] : 0;
        }
        __syncthreads();
        int c = cs[0], offmax = cs[1];
        int t0 = chunk * 32;
        int ts = max(t0, 1), te = min(t0 + 31, offmax);
        if (ts > te) return;
        int m = 0;
        while (m < c && offs[m] < ts) m++;
        const float4* sq = (const float4*)(seq + (size_t)b * S_ * H_) + tid;
        float4 acc = make_float4(0, 0, 0, 0);
        int t = ts;
        while (t + 7 <= te) {
            float4 v[8];
#pragma unroll
            for (int k = 0; k < 8; ++k) v[k] = sq[(size_t)(t + k) * (H_ / 4)];
#pragma unroll
            for (int k = 0; k < 8; ++k) {
                if (offs[m] < t + k) {
                    float* dst = node_sum + ((size_t)(b * M_ + m)) * H_ + tid * 4;
                    atomicAdd(dst + 0, acc.x); atomicAdd(dst + 1, acc.y);
                    atomicAdd(dst + 2, acc.z); atomicAdd(dst + 3, acc.w);
                    acc = make_float4(0, 0, 0, 0);
                    while (offs[m] < t + k) m++;
                }
                acc.x += v[k].x; acc.y += v[k].y; acc.z += v[k].z; acc.w += v[k].w;
            }
            t += 8;
        }
        for (; t <= te; ++t) {
            if (offs[m] < t) {
                float* dst = node_sum + ((size_t)(b * M_ + m)) * H_ + tid * 4;
                atomicAdd(dst + 0, acc.x); atomicAdd(dst + 1, acc.y);
                atomicAdd(dst + 2, acc.z); atomicAdd(dst + 3, acc.w);
                acc = make_float4(0, 0, 0, 0);
                while (offs[m] < t) m++;
            }
            float4 v = sq[(size_t)t * (H_ / 4)];
            acc.x += v.x; acc.y += v.y; acc.z += v.z; acc.w += v.w;
        }
        float* dst = node_sum + ((size_t)(b * M_ + m)) * H_ + tid * 4;
        atomicAdd(dst + 0, acc.x); atomicAdd(dst + 1, acc.y);
        atomicAdd(dst + 2, acc.z); atomicAdd(dst + 3, acc.w);
    } else if (bid < 4096) {
        // ---- prep: Wt (3072 x 1024 bf16) = transposed [Wnd ; W1+W3 ; W2-W3] ----
        float (*T)[33] = (float(*)[33])smem;
        int e = bid - 1024;
        int s = e >> 10, rem = e & 1023;
        int bx = rem & 31, by = rem >> 5;
        int c = tid & 31, r0 = tid >> 5;
        const int HH = H_ * H_;
#pragma unroll
        for (int i = 0; i < 4; ++i) {
            int r = r0 + 8 * i;
            size_t k = by * 32 + r, n = bx * 32 + c;
            float v;
            if (s == 0)      v = Wnd[k * H_ + n];
            else if (s == 1) v = Wed[k * H_ + n] + Wed[2 * HH + k * H_ + n];
            else             v = Wed[HH + k * H_ + n] - Wed[2 * HH + k * H_ + n];
            T[r][c] = v;
        }
        __syncthreads();
#pragma unroll
        for (int i = 0; i < 4; ++i) {
            int rr = r0 + 8 * i;
            Wt[(size_t)(s * H_ + bx * 32 + rr) * H_ + by * 32 + c] = __float2bfloat16(T[c][rr]);
        }
    } else if (bid == 4096) {
        // ---- count ----
        if (tid < 64) {
            int b = tid;
            int c = 0;
            for (int m = 0; m < M_ - 1; ++m) c += (off[b * (M_ - 1) + m] > 0) ? 1 : 0;
            count[b] = c;
        }
    } else if (bid == 4097) {
        // ---- invalid-edge constant logits: tanh(b_ed) @ W_eo + b_eo ----
        float* s0 = smem; float* s1 = smem + 256;
        float a0 = 0.f, a1 = 0.f;
        for (int h = tid; h < H_; h += 256) {
            float t = tanh_fast(bed[h]);
            a0 += t * Weo[h * 2 + 0];
            a1 += t * Weo[h * 2 + 1];
        }
        s0[tid] = a0; s1[tid] = a1; __syncthreads();
        for (int o = 128; o > 0; o >>= 1) {
            if (tid < o) { s0[tid] += s0[tid + o]; s1[tid] += s1[tid + o]; }
            __syncthreads();
        }
        if (tid == 0) { econ[0] = s0[0] + beo[0]; econ[1] = s1[0] + beo[1]; }
    } else {
        // ---- cls GEMM split-K: accumulate cls@W into ZEROED naf|cdh ----
        float (*As)[64] = (float(*)[64])smem;
        float (*Bs)[64] = (float(*)[64])(smem + 1024);
        int e = bid - 4098;
        int bx = e & 31;
        int kbase = (e >> 5) * 128;
        const float* W;
        float* dst;
        int cbase;
        if (bx < 16) { W = Wnaf; dst = naf; cbase = bx * 64; }
        else         { W = Wcd;  dst = cdh; cbase = (bx - 16) * 64; }
        int tx = tid % 16, ty = tid / 16;
        float c[4][4] = {};
        int la_row = tid / 4;
        int la_k4  = (tid % 4) * 4;
        int lb_k   = tid / 16;
        int lb_c4  = (tid % 16) * 4;
        for (int k0 = 0; k0 < 128; k0 += 16) {
            float4 a = *(const float4*)(seq + (size_t)la_row * S_ * H_ + kbase + k0 + la_k4);
            *(float4*)(&Bs[lb_k][lb_c4]) =
                *(const float4*)(W + (size_t)(kbase + k0 + lb_k) * H_ + cbase + lb_c4);
            As[la_k4 + 0][la_row] = a.x;
            As[la_k4 + 1][la_row] = a.y;
            As[la_k4 + 2][la_row] = a.z;
            As[la_k4 + 3][la_row] = a.w;
            __syncthreads();
#pragma unroll
            for (int kk = 0; kk < 16; ++kk) {
                float4 av = *(const float4*)(&As[kk][ty * 4]);
                float4 bv = *(const float4*)(&Bs[kk][tx * 4]);
                c[0][0] += av.x * bv.x; c[0][1] += av.x * bv.y; c[0][2] += av.x * bv.z; c[0][3] += av.x * bv.w;
                c[1][0] += av.y * bv.x; c[1][1] += av.y * bv.y; c[1][2] += av.y * bv.z; c[1][3] += av.y * bv.w;
                c[2][0] += av.z * bv.x; c[2][1] += av.z * bv.y; c[2][2] += av.z * bv.z; c[2][3] += av.z * bv.w;
                c[3][0] += av.w * bv.x; c[3][1] += av.w * bv.y; c[3][2] += av.w * bv.z; c[3][3] += av.w * bv.w;
            }
            __syncthreads();
        }
#pragma unroll
        for (int i = 0; i < 4; ++i)
#pragma unroll
            for (int j = 0; j < 4; ++j)
                atomicAdd(dst + (size_t)(ty * 4 + i) * H_ + cbase + tx * 4 + j, c[i][j]);
    }
}

// ================= STAGE 2: finalize -> bf16 node matrix | cls logits =================
__global__ __launch_bounds__(256) void k_stage2(
    const float* __restrict__ sums, const int* __restrict__ off,
    const int* __restrict__ count, const float* __restrict__ naf,
    const float* __restrict__ bnaf, __hip_bfloat16* __restrict__ nodeB,
    const float* __restrict__ cdh, const float* __restrict__ bcd,
    const float* __restrict__ Wco, const float* __restrict__ bco,
    float* __restrict__ out) {
    __shared__ float smem[512];
    int bid = blockIdx.x;
    int tid = threadIdx.x;
    if (bid < 1664) {
        int b = bid / 26, m = bid - b * 26;
        int cnt = count[b];
        float4 v = make_float4(0, 0, 0, 0);
        const float4* row = (const float4*)(sums + ((size_t)(b * M_ + m)) * H_);
        if (m < M_ - 1) {
            int o = off[b * (M_ - 1) + m];
            if (o > 0) {
                int prev = (m > 0) ? off[b * (M_ - 1) + m - 1] : 0;
                float inv = 1.0f / (float)max(o - prev, 1);
                float4 s = row[tid];
                v = make_float4(s.x * inv, s.y * inv, s.z * inv, s.w * inv);
            }
        }
        if (m == cnt) {
            float4 a = ((const float4*)(naf + (size_t)b * H_))[tid];
            float4 bb = ((const float4*)bnaf)[tid];
            v.x += a.x + bb.x; v.y += a.y + bb.y; v.z += a.z + bb.z; v.w += a.w + bb.w;
        }
        __hip_bfloat16 __attribute__((aligned(8))) h[4] = {
            __float2bfloat16(v.x), __float2bfloat16(v.y),
            __float2bfloat16(v.z), __float2bfloat16(v.w)};
        *(ushort4*)(nodeB + ((size_t)(b * M_ + m)) * H_ + tid * 4) = *(const ushort4*)h;
    } else {
        int b = bid - 1664;
        float* s0 = smem; float* s1 = smem + 256;
        float a0 = 0.f, a1 = 0.f;
        for (int h = tid; h < H_; h += 256) {
            float t = tanh_fast(cdh[(size_t)b * H_ + h] + bcd[h]);
            a0 += t * Wco[h * 2 + 0];
            a1 += t * Wco[h * 2 + 1];
        }
        s0[tid] = a0; s1[tid] = a1; __syncthreads();
        for (int o = 128; o > 0; o >>= 1) {
            if (tid < o) { s0[tid] += s0[tid + o]; s1[tid] += s1[tid + o]; }
            __syncthreads();
        }
        if (tid == 0) { out[b * 2 + 0] = s0[0] + bco[0]; out[b * 2 + 1] = s1[0] + bco[1]; }
    }
}

// ================= STAGE 3: MFMA GEMM C(1664x3072) = nodeB @ Wt^T =================
#define GM 1664
#define GN 3072
#define GK 1024
__global__ __launch_bounds__(256) void k_mfma(const __hip_bfloat16* __restrict__ A,
                                              const __hip_bfloat16* __restrict__ Bt,
                                              float* __restrict__ C) {
    __shared__ __hip_bfloat16 As[128 * 32];
    __shared__ __hip_bfloat16 Bs[128 * 32];
    int tid = threadIdx.x;
    int wid = tid >> 6, ln = tid & 63;
    int row0 = blockIdx.y * 128, col0 = blockIdx.x * 128;
    const __hip_bfloat16* ga = A + (size_t)(row0 + wid * 16 + (ln >> 2)) * GK + (ln & 3) * 8;
    const __hip_bfloat16* gb = Bt + (size_t)(col0 + wid * 16 + (ln >> 2)) * GK + (ln & 3) * 8;
    __hip_bfloat16* lA = As + wid * 512;
    __hip_bfloat16* lB = Bs + wid * 512;
    int mrow = (wid >> 1) * 64, ncol = (wid & 1) * 64;
    int l15 = ln & 15, l4 = ln >> 4;
    f32x4 acc[4][4] = {};
    const __hip_bfloat16* pa = As + (size_t)(mrow + l15) * 32 + l4 * 8;
    const __hip_bfloat16* pb = Bs + (size_t)(ncol + l15) * 32 + l4 * 8;
    for (int k0 = 0; k0 < GK; k0 += 32) {
        gload16(ga, lA);
        gload16(ga + 64 * GK, lA + 2048);
        gload16(gb, lB);
        gload16(gb + 64 * GK, lB + 2048);
        ga += 32; gb += 32;
        __syncthreads();
        bf16x8 af[4], bf[4];
#pragma unroll
        for (int mi = 0; mi < 4; ++mi) af[mi] = *(const bf16x8*)(pa + mi * 16 * 32);
#pragma unroll
        for (int ni = 0; ni < 4; ++ni) bf[ni] = *(const bf16x8*)(pb + ni * 16 * 32);
#pragma unroll
        for (int mi = 0; mi < 4; ++mi)
#pragma unroll
            for (int ni = 0; ni < 4; ++ni)
                acc[mi][ni] = __builtin_amdgcn_mfma_f32_16x16x32_bf16(af[mi], bf[ni],
                                                                      acc[mi][ni], 0, 0, 0);
        __syncthreads();
    }
#pragma unroll
    for (int mi = 0; mi < 4; ++mi)
#pragma unroll
        for (int ni = 0; ni < 4; ++ni) {
            f32x4 v = acc[mi][ni];
            size_t r = row0 + mrow + mi * 16 + l4 * 4;
            size_t cc = col0 + ncol + ni * 16 + l15;
            C[(r + 0) * GN + cc] = v[0];
            C[(r + 1) * GN + cc] = v[1];
            C[(r + 2) * GN + cc] = v[2];
            C[(r + 3) * GN + cc] = v[3];
        }
}

// ================= STAGE 4: node logits | edge logits =================
__global__ __launch_bounds__(256) void k_stage4(
    const float* __restrict__ Cm, const int* __restrict__ count,
    const float* __restrict__ bnd, const float* __restrict__ Wno,
    const float* __restrict__ bno, const float* __restrict__ bed,
    const float* __restrict__ Weo, const float* __restrict__ beo,
    const float* __restrict__ econ, float* __restrict__ out_n,
    float* __restrict__ out_e) {
    int bid = blockIdx.x;
    int wid = threadIdx.x >> 6, lane = threadIdx.x & 63;
    if (bid < 416) {
        int r = bid * 4 + wid;
        const float4* src = (const float4*)(Cm + (size_t)r * GN);
        float a0 = 0.f, a1 = 0.f;
#pragma unroll
        for (int it = 0; it < 4; ++it) {
            int h = lane * 4 + it * 256;
            float4 s = src[lane + it * 64];
            float4 bb = *(const float4*)(bnd + h);
            float t0 = tanh_fast(s.x + bb.x), t1 = tanh_fast(s.y + bb.y);
            float t2 = tanh_fast(s.z + bb.z), t3 = tanh_fast(s.w + bb.w);
            a0 += t0 * Wno[h * 2 + 0] + t1 * Wno[h * 2 + 2] + t2 * Wno[h * 2 + 4] + t3 * Wno[h * 2 + 6];
            a1 += t0 * Wno[h * 2 + 1] + t1 * Wno[h * 2 + 3] + t2 * Wno[h * 2 + 5] + t3 * Wno[h * 2 + 7];
        }
        for (int o = 32; o > 0; o >>= 1) { a0 += __shfl_down(a0, o); a1 += __shfl_down(a1, o); }
        if (lane == 0) { out_n[(size_t)r * 2 + 0] = a0 + bno[0]; out_n[(size_t)r * 2 + 1] = a1 + bno[1]; }
    } else {
        int e = bid - 416;
        int b = e >> 4;
        int wg = (e & 15) * 4 + wid;
        int n = count[b] + 1;
        int n2 = n * n;
        float4 bed4[4], w04[4], w14[4];
#pragma unroll
        for (int it = 0; it < 4; ++it) {
            int h = lane * 4 + it * 256;
            bed4[it] = *(const float4*)(bed + h);
            w04[it] = make_float4(Weo[h * 2 + 0], Weo[h * 2 + 2], Weo[h * 2 + 4], Weo[h * 2 + 6]);
            w14[it] = make_float4(Weo[h * 2 + 1], Weo[h * 2 + 3], Weo[h * 2 + 5], Weo[h * 2 + 7]);
        }
        float e0 = econ[0], e1 = econ[1];
        float b0 = beo[0], b1 = beo[1];
        for (int k = wg; k < E_; k += 64) {
            float* dst = out_e + ((size_t)b * E_ + k) * 2;
            if (k >= n2) {
                if (lane == 0) { dst[0] = e0; dst[1] = e1; }
                continue;
            }
            int i = k / n, j = k - i * n;
            const float4* U4 = (const float4*)(Cm + (size_t)(b * M_ + j) * GN + H_);
            const float4* V4 = (const float4*)(Cm + (size_t)(b * M_ + i) * GN + 2 * H_);
            float a0 = 0.f, a1 = 0.f;
#pragma unroll
            for (int it = 0; it < 4; ++it) {
                float4 u = U4[lane + it * 64];
                float4 v = V4[lane + it * 64];
                float t0 = tanh_fast(u.x + v.x + bed4[it].x);
                float t1 = tanh_fast(u.y + v.y + bed4[it].y);
                float t2 = tanh_fast(u.z + v.z + bed4[it].z);
                float t3 = tanh_fast(u.w + v.w + bed4[it].w);
                a0 += t0 * w04[it].x + t1 * w04[it].y + t2 * w04[it].z + t3 * w04[it].w;
                a1 += t0 * w14[it].x + t1 * w14[it].y + t2 * w14[it].z + t3 * w14[it].w;
            }
            for (int o = 32; o > 0; o >>= 1) { a0 += __shfl_down(a0, o); a1 += __shfl_down(a1, o); }
            if (lane == 0) { dst[0] = a0 + b0; dst[1] = a1 + b1; }
        }
    }
}

extern "C" void kernel_launch(void* const* d_in, const int* in_sizes, int n_in,
                              void* d_out, int out_size, void* d_ws, size_t ws_size,
                              hipStream_t stream) {
    const float* seq  = (const float*)d_in[0];
    const int*   off  = (const int*)d_in[1];
    const float* Wnaf = (const float*)d_in[4];  const float* bnaf = (const float*)d_in[5];
    const float* Wcd  = (const float*)d_in[6];  const float* bcd  = (const float*)d_in[7];
    const float* Wco  = (const float*)d_in[8];  const float* bco  = (const float*)d_in[9];
    const float* Wnd  = (const float*)d_in[10]; const float* bnd  = (const float*)d_in[11];
    const float* Wno  = (const float*)d_in[12]; const float* bno  = (const float*)d_in[13];
    const float* Wed  = (const float*)d_in[14]; const float* bed  = (const float*)d_in[15];
    const float* Weo  = (const float*)d_in[16]; const float* beo  = (const float*)d_in[17];
    float* out = (float*)d_out;

    float* ws = (float*)d_ws;
    size_t p = 0;
    float* nodeS = ws + p;  p += (size_t)B_ * M_ * H_;           // zeroed
    float* naf   = ws + p;  p += (size_t)B_ * H_;                // zeroed (acc only)
    float* cdh   = ws + p;  p += (size_t)B_ * H_;                // zeroed (acc only)
    __hip_bfloat16* nodeB = (__hip_bfloat16*)(ws + p); p += (size_t)B_ * M_ * H_ / 2;
    __hip_bfloat16* Wt    = (__hip_bfloat16*)(ws + p); p += (size_t)3 * H_ * H_ / 2;
    float* Cbuf  = ws + p;  p += (size_t)B_ * M_ * 3 * H_;
    int*   cnt   = (int*)(ws + p); p += 64;
    float* econ  = ws + p;  p += 2;

    hipMemsetAsync(nodeS, 0, ((size_t)B_ * M_ * H_ + 2 * (size_t)B_ * H_) * sizeof(float),
                   stream);

    k_stage1<<<dim3(4354), 256, 0, stream>>>(seq, off, Wnaf, Wcd, Wnd, Wed, bed, Weo, beo,
                                             Wt, cnt, econ, naf, cdh, nodeS);
    k_stage2<<<dim3(1728), 256, 0, stream>>>(nodeS, off, cnt, naf, bnaf, nodeB,
                                             cdh, bcd, Wco, bco, out);
    k_mfma<<<dim3(GN / 128, GM / 128), 256, 0, stream>>>(nodeB, Wt, Cbuf);
    k_stage4<<<dim3(1440), 256, 0, stream>>>(Cbuf, cnt, bnd, Wno, bno, bed, Weo, beo, econ,
                                             out + B_ * 2, out + B_ * 2 + B_ * M_ * 2);
}